// Round 2
// baseline (563.099 us; speedup 1.0000x reference)
//
#include <hip/hip_runtime.h>

#define BB 4
#define LL 4096
#define DD 128

typedef float f32x4 __attribute__((ext_vector_type(4)));
typedef short bf16x8 __attribute__((ext_vector_type(8)));
typedef unsigned short u16x8 __attribute__((ext_vector_type(8)));
typedef unsigned short u16x4 __attribute__((ext_vector_type(4)));
typedef int i32x4 __attribute__((ext_vector_type(4)));

__device__ __forceinline__ unsigned short f2bf(float f) {
  union { float f; unsigned u; } v; v.f = f;
  unsigned r = v.u + 0x7FFFu + ((v.u >> 16) & 1u);
  return (unsigned short)(r >> 16);
}

// ---- norms: qn[b*L+l] = sum_d Q^2 (fp32-exact), kn likewise ----
__global__ __launch_bounds__(256) void kNorm(const float* __restrict__ Q,
                                             const float* __restrict__ K,
                                             float* __restrict__ qn,
                                             float* __restrict__ kn) {
  int w = blockIdx.x * 4 + (threadIdx.x >> 6);
  int lane = threadIdx.x & 63;
  const float* src = (w < BB * LL) ? Q : K;
  float* dst = (w < BB * LL) ? qn : kn;
  int row = w & (BB * LL - 1);
  const float* p = src + (size_t)row * DD + lane * 2;
  float a = p[0], b = p[1];
  float s = a * a + b * b;
  #pragma unroll
  for (int m = 1; m < 64; m <<= 1) s += __shfl_xor(s, m);
  if (lane == 0) dst[row] = s;
}

// ---- convert Q,K to plain bf16 [b][l][d] ----
__global__ __launch_bounds__(256) void kCvt(const float* __restrict__ Q,
                                            const float* __restrict__ K,
                                            unsigned short* __restrict__ Qb,
                                            unsigned short* __restrict__ Kb) {
  const size_t NT = (size_t)BB * LL * DD / 8;
  size_t i = (size_t)blockIdx.x * 256 + threadIdx.x;
  const float* src = (i < NT) ? Q : K;
  unsigned short* dst = (i < NT) ? Qb : Kb;
  size_t j = (i < NT) ? i : (i - NT);
  f32x4 a = ((const f32x4*)src)[j * 2];
  f32x4 b = ((const f32x4*)src)[j * 2 + 1];
  u16x8 h;
  h[0] = f2bf(a.x); h[1] = f2bf(a.y); h[2] = f2bf(a.z); h[3] = f2bf(a.w);
  h[4] = f2bf(b.x); h[5] = f2bf(b.y); h[6] = f2bf(b.z); h[7] = f2bf(b.w);
  ((u16x8*)dst)[j] = h;
}

// ---- V transpose to bf16: VT[b][d][k] = bf16(V[b][k][d]) ----
__global__ __launch_bounds__(256) void kVT(const float* __restrict__ V,
                                           unsigned short* __restrict__ VT) {
  __shared__ unsigned short t[128][68];
  int bx = blockIdx.x;
  int kt = bx & 63, b = bx >> 6;
  int k0 = kt * 64;
  int tid = threadIdx.x;
  const float* Vb = V + ((size_t)b * LL + k0) * DD;
  #pragma unroll
  for (int i = 0; i < 8; ++i) {
    int flat = tid + i * 256;
    int row = flat >> 5, c4 = flat & 31;
    f32x4 v = *(const f32x4*)(Vb + row * DD + c4 * 4);
    #pragma unroll
    for (int j = 0; j < 4; ++j) t[c4 * 4 + j][row] = f2bf(v[j]);
  }
  __syncthreads();
  unsigned short* Ob = VT + (size_t)b * DD * LL + k0;
  #pragma unroll
  for (int i = 0; i < 8; ++i) {
    int flat = tid + i * 256;
    int d = flat >> 4, c = flat & 15;
    *(u16x4*)(Ob + (size_t)d * LL + c * 4) = *(const u16x4*)&t[d][c * 4];
  }
}

// ---- kernel A: swapped-operand QK^T -> dist2, scores, row-sum-exp ----
// grid 1024: qb(64) x b(4) x ks(4). 4 waves; wave w owns k rows [t*64+w*16,+16)
// for 16 tiles; covers all 64 q of the block. No staging LDS, no loop barriers.
// C-frag: k = kbase + lr*4 + reg (M), q = q0 + qs*16 + lc (N) -> f32x4 stores.
__global__ __launch_bounds__(256, 3) void kA(
    const unsigned short* __restrict__ Qb, const unsigned short* __restrict__ Kb,
    const int* __restrict__ mask, const float* __restrict__ qn,
    const float* __restrict__ kn, float* __restrict__ scores,
    float* __restrict__ dist2, float* __restrict__ l_part) {
  __shared__ float lds_l[4][64];
  int bx = blockIdx.x;
  int qb = bx & 63, b = (bx >> 6) & 3, ks = bx >> 8;
  int tid = threadIdx.x;
  int w = tid >> 6, lane = tid & 63, lr = lane >> 4, lc = lane & 15;
  int q0 = qb * 64;
  size_t bL = (size_t)b * LL;

  bf16x8 qf[4][4];   // B-operand: Q fragments (N-row = lc = q)
  float qn_r[4];
  size_t rowb[4];
  #pragma unroll
  for (int qs = 0; qs < 4; ++qs) {
    int q = q0 + qs * 16 + lc;
    qn_r[qs] = qn[bL + q];
    rowb[qs] = (bL + q) * (size_t)LL;
    const unsigned short* qp = Qb + (bL + q) * DD;
    #pragma unroll
    for (int c = 0; c < 4; ++c)
      qf[qs][c] = *(const bf16x8*)(qp + c * 32 + lr * 8);
  }

  float l_acc[4] = {0.f, 0.f, 0.f, 0.f};

  for (int t = 0; t < 16; ++t) {
    int kbase = ks * 1024 + t * 64 + w * 16;
    const unsigned short* kp = Kb + (bL + kbase + lc) * DD;  // A: M-row = lc = k
    bf16x8 af[4];
    #pragma unroll
    for (int c = 0; c < 4; ++c)
      af[c] = *(const bf16x8*)(kp + c * 32 + lr * 8);
    f32x4 kn4 = *(const f32x4*)(kn + bL + kbase + lr * 4);
    #pragma unroll
    for (int qs = 0; qs < 4; ++qs) {
      size_t off = rowb[qs] + kbase + lr * 4;
      i32x4 m4 = *(const i32x4*)(mask + off);
      f32x4 S = (f32x4){0.f, 0.f, 0.f, 0.f};
      #pragma unroll
      for (int c = 0; c < 4; ++c)
        S = __builtin_amdgcn_mfma_f32_16x16x32_bf16(af[c], qf[qs][c], S, 0, 0, 0);
      f32x4 d2, sv;
      float le = 0.f;
      #pragma unroll
      for (int r = 0; r < 4; ++r) {
        float d = qn_r[qs] + kn4[r] - 2.0f * S[r];
        d2[r] = d;
        float sc = d * (-1.0f / 256.0f);
        bool ms = (m4[r] == 0);
        sv[r] = ms ? -__builtin_inff() : sc;
        le += ms ? 0.f : __expf(sc);
      }
      *(f32x4*)(dist2 + off) = d2;
      *(f32x4*)(scores + off) = sv;
      l_acc[qs] += le;
    }
  }
  // reduce row sums: over lr (lanes differing in bits 4,5), then over waves
  #pragma unroll
  for (int qs = 0; qs < 4; ++qs) {
    float v = l_acc[qs];
    v += __shfl_xor(v, 16);
    v += __shfl_xor(v, 32);
    l_acc[qs] = v;
  }
  if (lane < 16) {
    #pragma unroll
    for (int qs = 0; qs < 4; ++qs) lds_l[w][qs * 16 + lane] = l_acc[qs];
  }
  __syncthreads();
  if (tid < 64) {
    float s = lds_l[0][tid] + lds_l[1][tid] + lds_l[2][tid] + lds_l[3][tid];
    l_part[(size_t)ks * (BB * LL) + bL + q0 + tid] = s;
  }
}

// ---- kernel B: attn = exp(scores)*rl (fused with A-frag load), O += P@V^T ----
// grid 1024: qb(64) x b(4) x ks(4). Wave w owns q rows [qb*64+w*16,+16), all
// barrier-free; V-frags stream from L2-resident VT; 1/l applied in epilogue.
__global__ __launch_bounds__(256, 4) void kB(
    const float* __restrict__ scores, const float* __restrict__ l_part,
    const unsigned short* __restrict__ VT, float* __restrict__ attn,
    float* __restrict__ O_part) {
  int bx = blockIdx.x;
  int qb = bx & 63, b = (bx >> 6) & 3, ks = bx >> 8;
  int tid = threadIdx.x;
  int w = tid >> 6, lane = tid & 63, lr = lane >> 4, lc = lane & 15;
  int qg = qb * 64 + w * 16;
  size_t bL = (size_t)b * LL;

  float s = 0.f;
  #pragma unroll
  for (int sp = 0; sp < 4; ++sp)
    s += l_part[(size_t)sp * (BB * LL) + bL + qg + lc];
  float rl = 1.0f / s;

  f32x4 o[8];
  #pragma unroll
  for (int f = 0; f < 8; ++f) o[f] = (f32x4){0.f, 0.f, 0.f, 0.f};

  const float* Sb = scores + (bL + qg + lc) * (size_t)LL;  // lane's own q row
  float* Ab = attn + (bL + qg + lc) * (size_t)LL;
  const unsigned short* Vb = VT + (size_t)b * DD * LL;

  for (int t = 0; t < 16; ++t) {
    int k0 = ks * 1024 + t * 64;
    bf16x8 pa[2];
    #pragma unroll
    for (int c = 0; c < 2; ++c) {
      int ko = k0 + c * 32 + lr * 8;
      f32x4 s0 = *(const f32x4*)(Sb + ko);
      f32x4 s1 = *(const f32x4*)(Sb + ko + 4);
      float e0 = __expf(s0.x), e1 = __expf(s0.y), e2 = __expf(s0.z), e3 = __expf(s0.w);
      float e4 = __expf(s1.x), e5 = __expf(s1.y), e6 = __expf(s1.z), e7 = __expf(s1.w);
      f32x4 a0 = (f32x4){e0 * rl, e1 * rl, e2 * rl, e3 * rl};
      f32x4 a1 = (f32x4){e4 * rl, e5 * rl, e6 * rl, e7 * rl};
      *(f32x4*)(Ab + ko) = a0;
      *(f32x4*)(Ab + ko + 4) = a1;
      bf16x8 p;
      p[0] = (short)f2bf(e0); p[1] = (short)f2bf(e1);
      p[2] = (short)f2bf(e2); p[3] = (short)f2bf(e3);
      p[4] = (short)f2bf(e4); p[5] = (short)f2bf(e5);
      p[6] = (short)f2bf(e6); p[7] = (short)f2bf(e7);
      pa[c] = p;
    }
    #pragma unroll
    for (int f = 0; f < 8; ++f) {
      const unsigned short* vp = Vb + (size_t)(f * 16 + lc) * LL + k0 + lr * 8;
      #pragma unroll
      for (int c = 0; c < 2; ++c) {
        bf16x8 vb = *(const bf16x8*)(vp + c * 32);
        o[f] = __builtin_amdgcn_mfma_f32_16x16x32_bf16(pa[c], vb, o[f], 0, 0, 0);
      }
    }
  }
  float rlv[4];
  #pragma unroll
  for (int r = 0; r < 4; ++r) rlv[r] = __shfl(rl, lr * 4 + r);
  float* Ob = O_part + (size_t)ks * ((size_t)BB * LL * DD);
  #pragma unroll
  for (int f = 0; f < 8; ++f) {
    #pragma unroll
    for (int r = 0; r < 4; ++r)
      Ob[(bL + qg + lr * 4 + r) * DD + f * 16 + lc] = o[f][r] * rlv[r];
  }
}

// ---- reduce the four O partials into out ----
__global__ __launch_bounds__(256) void kR(const float* __restrict__ O_part,
                                          float* __restrict__ out) {
  size_t idx = (size_t)blockIdx.x * 256 + threadIdx.x;
  const size_t N4 = (size_t)BB * LL * DD / 4;
  const f32x4* a = (const f32x4*)O_part;
  f32x4 v = a[idx] + a[idx + N4] + a[idx + 2 * N4] + a[idx + 3 * N4];
  ((f32x4*)out)[idx] = v;
}

extern "C" void kernel_launch(void* const* d_in, const int* in_sizes, int n_in,
                              void* d_out, int out_size, void* d_ws, size_t ws_size,
                              hipStream_t stream) {
  const float* Q = (const float*)d_in[0];
  const float* K = (const float*)d_in[1];
  const float* V = (const float*)d_in[2];
  const int* mask = (const int*)d_in[3];

  float* out = (float*)d_out;                        // [4,4096,128]
  float* attn = out + (size_t)BB * LL * DD;          // [4,4096,4096]
  float* scores = attn + (size_t)BB * LL * LL;       // [4,4096,4096]
  float* dist2 = scores + (size_t)BB * LL * LL;      // [4,4096,4096]

  float* qn = (float*)d_ws;                                   // 16384 f
  float* kn = qn + BB * LL;                                   // 16384 f
  float* l_part = kn + BB * LL;                               // 4*16384 f
  unsigned short* Qbf = (unsigned short*)(l_part + 4 * BB * LL);   // 4 MB
  unsigned short* Kbf = Qbf + (size_t)BB * LL * DD;                // 4 MB
  unsigned short* VTb = Kbf + (size_t)BB * LL * DD;                // 4 MB
  float* O_part = (float*)(VTb + (size_t)BB * LL * DD);            // 4 x 8 MB

  hipLaunchKernelGGL(kNorm, dim3(8192), dim3(256), 0, stream, Q, K, qn, kn);
  hipLaunchKernelGGL(kCvt, dim3(2048), dim3(256), 0, stream, Q, K, Qbf, Kbf);
  hipLaunchKernelGGL(kVT, dim3(256), dim3(256), 0, stream, V, VTb);
  hipLaunchKernelGGL(kA, dim3(1024), dim3(256), 0, stream, Qbf, Kbf, mask, qn,
                     kn, scores, dist2, l_part);
  hipLaunchKernelGGL(kB, dim3(1024), dim3(256), 0, stream, scores, l_part, VTb,
                     attn, O_part);
  hipLaunchKernelGGL(kR, dim3(2048), dim3(256), 0, stream, O_part, out);
}